// Round 1
// baseline (5651.068 us; speedup 1.0000x reference)
//
#include <hip/hip_runtime.h>

#define N_NODES 100000
#define E_EDGES 1600000
#define IN_DIM 64
#define HID_DIM 64
#define CLS_DIM 16

// ---------------- degree / norm ----------------

__global__ void deg_kernel(const int* __restrict__ row, const int* __restrict__ col,
                           unsigned int* __restrict__ deg) {
    int e = blockIdx.x * blockDim.x + threadIdx.x;
    if (e >= E_EDGES) return;
    int r = row[e], c = col[e];
    if (r != c) atomicAdd(&deg[r], 1u);
}

__global__ void dis_kernel(float* __restrict__ degdis) {
    int i = blockIdx.x * blockDim.x + threadIdx.x;
    if (i >= N_NODES) return;
    unsigned int d = ((const unsigned int*)degdis)[i];
    degdis[i] = (d > 0u) ? rsqrtf((float)d) : 0.0f;
}

// ---------------- SpMM: vout[r] += w_e * vin[c], scatter with atomics ----------------
// thread = (edge, quad of 4 dims); D = 64 fixed.

__global__ void spmm_kernel(const int* __restrict__ row, const int* __restrict__ col,
                            const float* __restrict__ dis,
                            const float* __restrict__ vin, float* __restrict__ vout) {
    long long idx = (long long)blockIdx.x * blockDim.x + threadIdx.x;
    int e = (int)(idx >> 4);
    int q = (int)(idx & 15);
    if (e >= E_EDGES) return;
    int r = row[e], c = col[e];
    if (r == c) return;
    float w = -dis[r] * dis[c];
    if (w == 0.0f) return;
    const float4 v = *(const float4*)(vin + (size_t)c * 64 + q * 4);
    float* o = vout + (size_t)r * 64 + q * 4;
    atomicAdd(o + 0, w * v.x);
    atomicAdd(o + 1, w * v.y);
    atomicAdd(o + 2, w * v.z);
    atomicAdd(o + 3, w * v.w);
}

// ---------------- fused 3-term GEMM + bias (+ReLU) ----------------
// out[n,j] = sum_k t0[n,k]*W[0,k,j] + t1[n,k]*W[1,k,j] + (2*braw[n,k]-t0[n,k])*W[2,k,j] + bias[j]
// One thread per node; W staged in LDS (uniform broadcast reads).

template <int OUT, bool RELU>
__global__ void gemm3_kernel(const float* __restrict__ t0p, const float* __restrict__ t1p,
                             const float* __restrict__ brawp,
                             const float* __restrict__ W, const float* __restrict__ bias,
                             float* __restrict__ out) {
    __shared__ float Ws[3 * 64 * OUT];
    for (int i = threadIdx.x; i < 3 * 64 * OUT; i += blockDim.x) Ws[i] = W[i];
    __syncthreads();

    int n = blockIdx.x * blockDim.x + threadIdx.x;
    if (n >= N_NODES) return;

    float acc[OUT];
#pragma unroll
    for (int j = 0; j < OUT; j++) acc[j] = bias[j];

    const float4* x0 = (const float4*)(t0p + (size_t)n * 64);
    const float4* x1 = (const float4*)(t1p + (size_t)n * 64);
    const float4* xb = (const float4*)(brawp + (size_t)n * 64);

#pragma unroll 4
    for (int k4 = 0; k4 < 16; k4++) {
        float4 a0 = x0[k4];
        float4 a1 = x1[k4];
        float4 ab = xb[k4];
        float t0v[4] = {a0.x, a0.y, a0.z, a0.w};
        float t1v[4] = {a1.x, a1.y, a1.z, a1.w};
        float tbv[4] = {ab.x, ab.y, ab.z, ab.w};
#pragma unroll
        for (int kk = 0; kk < 4; kk++) {
            int k = k4 * 4 + kk;
            float t0 = t0v[kk];
            float t1 = t1v[kk];
            float t2 = 2.0f * tbv[kk] - t0;
            const float* w0 = &Ws[k * OUT];
            const float* w1 = &Ws[64 * OUT + k * OUT];
            const float* w2 = &Ws[2 * 64 * OUT + k * OUT];
#pragma unroll
            for (int j = 0; j < OUT; j++)
                acc[j] += t0 * w0[j] + t1 * w1[j] + t2 * w2[j];
        }
    }

    float4* o4 = (float4*)(out + (size_t)n * OUT);
#pragma unroll
    for (int j4 = 0; j4 < OUT / 4; j4++) {
        float4 v;
        v.x = acc[j4 * 4 + 0];
        v.y = acc[j4 * 4 + 1];
        v.z = acc[j4 * 4 + 2];
        v.w = acc[j4 * 4 + 3];
        if (RELU) {
            v.x = fmaxf(v.x, 0.0f);
            v.y = fmaxf(v.y, 0.0f);
            v.z = fmaxf(v.z, 0.0f);
            v.w = fmaxf(v.w, 0.0f);
        }
        o4[j4] = v;
    }
}

// ---------------- launch ----------------

extern "C" void kernel_launch(void* const* d_in, const int* in_sizes, int n_in,
                              void* d_out, int out_size, void* d_ws, size_t ws_size,
                              hipStream_t stream) {
    const float* x  = (const float*)d_in[0];
    const int* edge = (const int*)d_in[1];
    const float* W1 = (const float*)d_in[2];
    const float* b1 = (const float*)d_in[3];
    const float* W2 = (const float*)d_in[4];
    const float* b2 = (const float*)d_in[5];
    float* out = (float*)d_out;

    const int* row = edge;            // edge_index[0]
    const int* col = edge + E_EDGES;  // edge_index[1]

    char* ws = (char*)d_ws;
    float* dis = (float*)ws;  // N floats (first used as uint deg)
    size_t off = (((size_t)N_NODES * 4) + 255) & ~(size_t)255;
    float* A = (float*)(ws + off);          // N*64
    float* B = A + (size_t)N_NODES * 64;    // N*64
    float* C = B + (size_t)N_NODES * 64;    // N*64 (hidden h)

    const size_t featBytes = (size_t)N_NODES * 64 * sizeof(float);
    const int spmmBlocks = (int)(((long long)E_EDGES * 16 + 255) / 256);
    const int nodeBlocks = (N_NODES + 255) / 256;
    const int edgeBlocks = (E_EDGES + 255) / 256;

    // norm
    hipMemsetAsync(dis, 0, N_NODES * sizeof(float), stream);
    deg_kernel<<<edgeBlocks, 256, 0, stream>>>(row, col, (unsigned int*)dis);
    dis_kernel<<<nodeBlocks, 256, 0, stream>>>(dis);

    // layer 1: A = lhat(x); B = lhat(A); C = relu(x@W1_0 + A@W1_1 + (2B-x)@W1_2 + b1)
    hipMemsetAsync(A, 0, featBytes, stream);
    spmm_kernel<<<spmmBlocks, 256, 0, stream>>>(row, col, dis, x, A);
    hipMemsetAsync(B, 0, featBytes, stream);
    spmm_kernel<<<spmmBlocks, 256, 0, stream>>>(row, col, dis, A, B);
    gemm3_kernel<64, true><<<nodeBlocks, 256, 0, stream>>>(x, A, B, W1, b1, C);

    // layer 2: A = lhat(C); B = lhat(A); out = C@W2_0 + A@W2_1 + (2B-C)@W2_2 + b2
    hipMemsetAsync(A, 0, featBytes, stream);
    spmm_kernel<<<spmmBlocks, 256, 0, stream>>>(row, col, dis, C, A);
    hipMemsetAsync(B, 0, featBytes, stream);
    spmm_kernel<<<spmmBlocks, 256, 0, stream>>>(row, col, dis, A, B);
    gemm3_kernel<16, false><<<nodeBlocks, 256, 0, stream>>>(C, A, B, W2, b2, out);
}

// Round 2
// 899.245 us; speedup vs baseline: 6.2842x; 6.2842x over previous
//
#include <hip/hip_runtime.h>

#define N_NODES 100000
#define E_EDGES 1600000

// ---------------- degree ----------------

__global__ void deg_kernel(const int* __restrict__ row, const int* __restrict__ col,
                           unsigned int* __restrict__ deg) {
    int e = blockIdx.x * blockDim.x + threadIdx.x;
    if (e >= E_EDGES) return;
    int r = row[e], c = col[e];
    if (r != c) atomicAdd(&deg[r], 1u);
}

__global__ void dis_kernel(const unsigned int* __restrict__ deg, float* __restrict__ dis) {
    int i = blockIdx.x * blockDim.x + threadIdx.x;
    if (i >= N_NODES) return;
    unsigned int d = deg[i];
    dis[i] = (d > 0u) ? rsqrtf((float)d) : 0.0f;
}

// ---------------- exclusive scan of deg -> rowptr (3 kernels) ----------------

__global__ void scan1_kernel(const unsigned int* __restrict__ deg,
                             unsigned int* __restrict__ rowptr,
                             unsigned int* __restrict__ bsum) {
    __shared__ unsigned int tmp[256];
    int i = blockIdx.x * 256 + threadIdx.x;
    unsigned int v = (i < N_NODES) ? deg[i] : 0u;
    tmp[threadIdx.x] = v;
    __syncthreads();
    for (int ofs = 1; ofs < 256; ofs <<= 1) {
        unsigned int t = (threadIdx.x >= ofs) ? tmp[threadIdx.x - ofs] : 0u;
        __syncthreads();
        tmp[threadIdx.x] += t;
        __syncthreads();
    }
    if (i < N_NODES) rowptr[i] = tmp[threadIdx.x] - v;  // local exclusive
    if (threadIdx.x == 255) bsum[blockIdx.x] = tmp[255];
}

__global__ void scan2_kernel(unsigned int* __restrict__ bsum, int nb) {
    __shared__ unsigned int tmp[512];
    unsigned int v = (threadIdx.x < nb) ? bsum[threadIdx.x] : 0u;
    tmp[threadIdx.x] = v;
    __syncthreads();
    for (int ofs = 1; ofs < 512; ofs <<= 1) {
        unsigned int t = (threadIdx.x >= ofs) ? tmp[threadIdx.x - ofs] : 0u;
        __syncthreads();
        tmp[threadIdx.x] += t;
        __syncthreads();
    }
    if (threadIdx.x < nb) bsum[threadIdx.x] = tmp[threadIdx.x] - v;  // exclusive
}

__global__ void scan3_kernel(unsigned int* __restrict__ rowptr,
                             const unsigned int* __restrict__ bsum) {
    int i = blockIdx.x * 256 + threadIdx.x;
    if (i < N_NODES) rowptr[i] += bsum[blockIdx.x];
}

// ---------------- CSR fill: rowptr becomes INCLUSIVE scan after this ----------------

__global__ void fill_kernel(const int* __restrict__ row, const int* __restrict__ col,
                            const float* __restrict__ dis,
                            unsigned int* __restrict__ rowptr,
                            int* __restrict__ ccol, float* __restrict__ cw) {
    int e = blockIdx.x * blockDim.x + threadIdx.x;
    if (e >= E_EDGES) return;
    int r = row[e], c = col[e];
    if (r == c) return;
    float w = -dis[r] * dis[c];
    unsigned int pos = atomicAdd(&rowptr[r], 1u);
    ccol[pos] = c;
    cw[pos] = w;
}

// ---------------- SpMM (CSR gather): one wave per row, lane = dim ----------------

__global__ void spmm_csr_kernel(const unsigned int* __restrict__ rowptr,
                                const int* __restrict__ ccol, const float* __restrict__ cw,
                                const float* __restrict__ vin, float* __restrict__ vout) {
    int wid = blockIdx.x * 4 + (threadIdx.x >> 6);
    int lane = threadIdx.x & 63;
    if (wid >= N_NODES) return;
    unsigned int s = (wid == 0) ? 0u : rowptr[wid - 1];
    unsigned int epos = rowptr[wid];
    float acc = 0.0f;
    for (unsigned int e = s; e < epos; e++) {
        int c = ccol[e];
        float w = cw[e];
        acc += w * vin[(size_t)c * 64 + lane];
    }
    vout[(size_t)wid * 64 + lane] = acc;
}

// ---------------- fused 3-term GEMM + bias (+ReLU) ----------------

template <int OUT, bool RELU>
__global__ void gemm3_kernel(const float* __restrict__ t0p, const float* __restrict__ t1p,
                             const float* __restrict__ brawp,
                             const float* __restrict__ W, const float* __restrict__ bias,
                             float* __restrict__ out) {
    __shared__ float Ws[3 * 64 * OUT];
    for (int i = threadIdx.x; i < 3 * 64 * OUT; i += blockDim.x) Ws[i] = W[i];
    __syncthreads();

    int n = blockIdx.x * blockDim.x + threadIdx.x;
    if (n >= N_NODES) return;

    float acc[OUT];
#pragma unroll
    for (int j = 0; j < OUT; j++) acc[j] = bias[j];

    const float4* x0 = (const float4*)(t0p + (size_t)n * 64);
    const float4* x1 = (const float4*)(t1p + (size_t)n * 64);
    const float4* xb = (const float4*)(brawp + (size_t)n * 64);

#pragma unroll 4
    for (int k4 = 0; k4 < 16; k4++) {
        float4 a0 = x0[k4];
        float4 a1 = x1[k4];
        float4 ab = xb[k4];
        float t0v[4] = {a0.x, a0.y, a0.z, a0.w};
        float t1v[4] = {a1.x, a1.y, a1.z, a1.w};
        float tbv[4] = {ab.x, ab.y, ab.z, ab.w};
#pragma unroll
        for (int kk = 0; kk < 4; kk++) {
            int k = k4 * 4 + kk;
            float t0 = t0v[kk];
            float t1 = t1v[kk];
            float t2 = 2.0f * tbv[kk] - t0;
            const float* w0 = &Ws[k * OUT];
            const float* w1 = &Ws[64 * OUT + k * OUT];
            const float* w2 = &Ws[2 * 64 * OUT + k * OUT];
#pragma unroll
            for (int j = 0; j < OUT; j++)
                acc[j] += t0 * w0[j] + t1 * w1[j] + t2 * w2[j];
        }
    }

    float4* o4 = (float4*)(out + (size_t)n * OUT);
#pragma unroll
    for (int j4 = 0; j4 < OUT / 4; j4++) {
        float4 v;
        v.x = acc[j4 * 4 + 0];
        v.y = acc[j4 * 4 + 1];
        v.z = acc[j4 * 4 + 2];
        v.w = acc[j4 * 4 + 3];
        if (RELU) {
            v.x = fmaxf(v.x, 0.0f);
            v.y = fmaxf(v.y, 0.0f);
            v.z = fmaxf(v.z, 0.0f);
            v.w = fmaxf(v.w, 0.0f);
        }
        o4[j4] = v;
    }
}

// ---------------- launch ----------------

extern "C" void kernel_launch(void* const* d_in, const int* in_sizes, int n_in,
                              void* d_out, int out_size, void* d_ws, size_t ws_size,
                              hipStream_t stream) {
    const float* x  = (const float*)d_in[0];
    const int* edge = (const int*)d_in[1];
    const float* W1 = (const float*)d_in[2];
    const float* b1 = (const float*)d_in[3];
    const float* W2 = (const float*)d_in[4];
    const float* b2 = (const float*)d_in[5];
    float* out = (float*)d_out;

    const int* row = edge;            // edge_index[0]
    const int* col = edge + E_EDGES;  // edge_index[1]

    // workspace layout
    char* ws = (char*)d_ws;
    size_t off = 0;
    auto alloc = [&](size_t bytes) {
        void* p = ws + off;
        off = (off + bytes + 255) & ~(size_t)255;
        return p;
    };
    unsigned int* deg    = (unsigned int*)alloc(N_NODES * 4);
    float*        dis    = (float*)alloc(N_NODES * 4);
    unsigned int* rowptr = (unsigned int*)alloc(N_NODES * 4);
    unsigned int* bsum   = (unsigned int*)alloc(512 * 4);
    int*          ccol   = (int*)alloc((size_t)E_EDGES * 4);
    float*        cw     = (float*)alloc((size_t)E_EDGES * 4);
    float*        A      = (float*)alloc((size_t)N_NODES * 64 * 4);
    float*        B      = (float*)alloc((size_t)N_NODES * 64 * 4);
    float*        C      = (float*)alloc((size_t)N_NODES * 64 * 4);

    const int nodeBlocks = (N_NODES + 255) / 256;   // 391
    const int edgeBlocks = (E_EDGES + 255) / 256;   // 6250
    const int spmmBlocks = (N_NODES + 3) / 4;       // 4 waves/block, 1 wave/row

    // ---- build norm + CSR ----
    hipMemsetAsync(deg, 0, N_NODES * 4, stream);
    deg_kernel<<<edgeBlocks, 256, 0, stream>>>(row, col, deg);
    dis_kernel<<<nodeBlocks, 256, 0, stream>>>(deg, dis);
    scan1_kernel<<<nodeBlocks, 256, 0, stream>>>(deg, rowptr, bsum);
    scan2_kernel<<<1, 512, 0, stream>>>(bsum, nodeBlocks);
    scan3_kernel<<<nodeBlocks, 256, 0, stream>>>(rowptr, bsum);
    fill_kernel<<<edgeBlocks, 256, 0, stream>>>(row, col, dis, rowptr, ccol, cw);
    // rowptr is now the INCLUSIVE scan (row i spans [rowptr[i-1], rowptr[i]))

    // ---- layer 1 ----
    spmm_csr_kernel<<<spmmBlocks, 256, 0, stream>>>(rowptr, ccol, cw, x, A);
    spmm_csr_kernel<<<spmmBlocks, 256, 0, stream>>>(rowptr, ccol, cw, A, B);
    gemm3_kernel<64, true><<<nodeBlocks, 256, 0, stream>>>(x, A, B, W1, b1, C);

    // ---- layer 2 ----
    spmm_csr_kernel<<<spmmBlocks, 256, 0, stream>>>(rowptr, ccol, cw, C, A);
    spmm_csr_kernel<<<spmmBlocks, 256, 0, stream>>>(rowptr, ccol, cw, A, B);
    gemm3_kernel<16, false><<<nodeBlocks, 256, 0, stream>>>(C, A, B, W2, b2, out);
}

// Round 3
// 544.307 us; speedup vs baseline: 10.3821x; 1.6521x over previous
//
#include <hip/hip_runtime.h>

#define N_NODES 100000
#define E_EDGES 1600000
#define CSR_CAP (E_EDGES + 4 * N_NODES)  // padded capacity

// ---------------- degree ----------------

__global__ void deg_kernel(const int* __restrict__ row, const int* __restrict__ col,
                           unsigned int* __restrict__ deg) {
    int e = blockIdx.x * blockDim.x + threadIdx.x;
    if (e >= E_EDGES) return;
    int r = row[e], c = col[e];
    if (r != c) atomicAdd(&deg[r], 1u);
}

__global__ void dis_kernel(const unsigned int* __restrict__ deg, float* __restrict__ dis) {
    int i = blockIdx.x * blockDim.x + threadIdx.x;
    if (i >= N_NODES) return;
    unsigned int d = deg[i];
    dis[i] = (d > 0u) ? rsqrtf((float)d) : 0.0f;
}

// ---------------- exclusive scan of PADDED deg -> rowptr ----------------

__global__ void scan1_kernel(const unsigned int* __restrict__ deg,
                             unsigned int* __restrict__ rowptr,
                             unsigned int* __restrict__ bsum) {
    __shared__ unsigned int tmp[256];
    int i = blockIdx.x * 256 + threadIdx.x;
    unsigned int v = (i < N_NODES) ? ((deg[i] + 3u) & ~3u) : 0u;
    tmp[threadIdx.x] = v;
    __syncthreads();
    for (int ofs = 1; ofs < 256; ofs <<= 1) {
        unsigned int t = (threadIdx.x >= ofs) ? tmp[threadIdx.x - ofs] : 0u;
        __syncthreads();
        tmp[threadIdx.x] += t;
        __syncthreads();
    }
    if (i < N_NODES) rowptr[i] = tmp[threadIdx.x] - v;  // local exclusive (padded)
    if (threadIdx.x == 255) bsum[blockIdx.x] = tmp[255];
}

__global__ void scan2_kernel(unsigned int* __restrict__ bsum, int nb) {
    __shared__ unsigned int tmp[512];
    unsigned int v = (threadIdx.x < nb) ? bsum[threadIdx.x] : 0u;
    tmp[threadIdx.x] = v;
    __syncthreads();
    for (int ofs = 1; ofs < 512; ofs <<= 1) {
        unsigned int t = (threadIdx.x >= ofs) ? tmp[threadIdx.x - ofs] : 0u;
        __syncthreads();
        tmp[threadIdx.x] += t;
        __syncthreads();
    }
    if (threadIdx.x < nb) bsum[threadIdx.x] = tmp[threadIdx.x] - v;  // exclusive
}

__global__ void scan3_kernel(unsigned int* __restrict__ rowptr,
                             const unsigned int* __restrict__ bsum,
                             unsigned int* __restrict__ cursor) {
    int i = blockIdx.x * 256 + threadIdx.x;
    if (i < N_NODES) {
        unsigned int v = rowptr[i] + bsum[blockIdx.x];
        rowptr[i] = v;
        cursor[i] = v;
    }
}

// ---------------- CSR fill (into padded layout; pad slots pre-zeroed) ----------------

__global__ void fill_kernel(const int* __restrict__ row, const int* __restrict__ col,
                            const float* __restrict__ dis,
                            unsigned int* __restrict__ cursor,
                            int* __restrict__ ccol, float* __restrict__ cw) {
    int e = blockIdx.x * blockDim.x + threadIdx.x;
    if (e >= E_EDGES) return;
    int r = row[e], c = col[e];
    if (r == c) return;
    float w = -dis[r] * dis[c];
    unsigned int pos = atomicAdd(&cursor[r], 1u);
    ccol[pos] = c;
    cw[pos] = w;
}

// ---------------- SpMM 64-dim: one wave per row, lane = dim, 4-way unrolled ----------------

__global__ void spmm64_kernel(const unsigned int* __restrict__ rowptr,
                              const unsigned int* __restrict__ deg,
                              const int* __restrict__ ccol, const float* __restrict__ cw,
                              const float* __restrict__ vin, float* __restrict__ vout) {
    int wid = blockIdx.x * 4 + (threadIdx.x >> 6);
    int lane = threadIdx.x & 63;
    if (wid >= N_NODES) return;
    unsigned int s = rowptr[wid];
    int pd = (int)((deg[wid] + 3u) & ~3u);
    float a0 = 0.0f, a1 = 0.0f, a2 = 0.0f, a3 = 0.0f;
    for (int e = 0; e < pd; e += 4) {
        int c0 = ccol[s + e + 0];
        int c1 = ccol[s + e + 1];
        int c2 = ccol[s + e + 2];
        int c3 = ccol[s + e + 3];
        float w0 = cw[s + e + 0];
        float w1 = cw[s + e + 1];
        float w2 = cw[s + e + 2];
        float w3 = cw[s + e + 3];
        float v0 = vin[(size_t)c0 * 64 + lane];
        float v1 = vin[(size_t)c1 * 64 + lane];
        float v2 = vin[(size_t)c2 * 64 + lane];
        float v3 = vin[(size_t)c3 * 64 + lane];
        a0 += w0 * v0;
        a1 += w1 * v1;
        a2 += w2 * v2;
        a3 += w3 * v3;
    }
    vout[(size_t)wid * 64 + lane] = (a0 + a1) + (a2 + a3);
}

// ---------------- SpMM 16-dim with fused epilogues ----------------
// MODE 0: vout[n] = add[n] + 2 * (L v)[n]        (S = Q + 2 L R)
// MODE 1: vout[n] = add[n] + (L v)[n]            (out = P + L S)

template <int MODE>
__global__ void spmm16_kernel(const unsigned int* __restrict__ rowptr,
                              const unsigned int* __restrict__ deg,
                              const int* __restrict__ ccol, const float* __restrict__ cw,
                              const float* __restrict__ vin, const float* __restrict__ add,
                              float* __restrict__ vout) {
    int wid = blockIdx.x * 16 + (threadIdx.x >> 4);
    int l16 = threadIdx.x & 15;
    if (wid >= N_NODES) return;
    unsigned int s = rowptr[wid];
    int pd = (int)((deg[wid] + 3u) & ~3u);
    float a0 = 0.0f, a1 = 0.0f, a2 = 0.0f, a3 = 0.0f;
    for (int e = 0; e < pd; e += 4) {
        int c0 = ccol[s + e + 0];
        int c1 = ccol[s + e + 1];
        int c2 = ccol[s + e + 2];
        int c3 = ccol[s + e + 3];
        float w0 = cw[s + e + 0];
        float w1 = cw[s + e + 1];
        float w2 = cw[s + e + 2];
        float w3 = cw[s + e + 3];
        a0 += w0 * vin[(size_t)c0 * 16 + l16];
        a1 += w1 * vin[(size_t)c1 * 16 + l16];
        a2 += w2 * vin[(size_t)c2 * 16 + l16];
        a3 += w3 * vin[(size_t)c3 * 16 + l16];
    }
    float acc = (a0 + a1) + (a2 + a3);
    float base = add[(size_t)wid * 16 + l16];
    vout[(size_t)wid * 16 + l16] = (MODE == 0) ? (base + 2.0f * acc) : (base + acc);
}

// ---------------- layer-1 fused 3-term GEMM + bias + ReLU ----------------

__global__ void gemm3_64_kernel(const float* __restrict__ t0p, const float* __restrict__ t1p,
                                const float* __restrict__ brawp,
                                const float* __restrict__ W, const float* __restrict__ bias,
                                float* __restrict__ out) {
    __shared__ float Ws[3 * 64 * 64];
    for (int i = threadIdx.x; i < 3 * 64 * 64; i += blockDim.x) Ws[i] = W[i];
    __syncthreads();

    int n = blockIdx.x * blockDim.x + threadIdx.x;
    if (n >= N_NODES) return;

    float acc[64];
#pragma unroll
    for (int j = 0; j < 64; j++) acc[j] = bias[j];

    const float4* x0 = (const float4*)(t0p + (size_t)n * 64);
    const float4* x1 = (const float4*)(t1p + (size_t)n * 64);
    const float4* xb = (const float4*)(brawp + (size_t)n * 64);

#pragma unroll 4
    for (int k4 = 0; k4 < 16; k4++) {
        float4 a0 = x0[k4];
        float4 a1 = x1[k4];
        float4 ab = xb[k4];
        float t0v[4] = {a0.x, a0.y, a0.z, a0.w};
        float t1v[4] = {a1.x, a1.y, a1.z, a1.w};
        float tbv[4] = {ab.x, ab.y, ab.z, ab.w};
#pragma unroll
        for (int kk = 0; kk < 4; kk++) {
            int k = k4 * 4 + kk;
            float t0 = t0v[kk];
            float t1 = t1v[kk];
            float t2 = 2.0f * tbv[kk] - t0;
            const float* w0 = &Ws[k * 64];
            const float* w1 = &Ws[64 * 64 + k * 64];
            const float* w2 = &Ws[2 * 64 * 64 + k * 64];
#pragma unroll
            for (int j = 0; j < 64; j++)
                acc[j] += t0 * w0[j] + t1 * w1[j] + t2 * w2[j];
        }
    }

    float4* o4 = (float4*)(out + (size_t)n * 64);
#pragma unroll
    for (int j4 = 0; j4 < 16; j4++) {
        float4 v;
        v.x = fmaxf(acc[j4 * 4 + 0], 0.0f);
        v.y = fmaxf(acc[j4 * 4 + 1], 0.0f);
        v.z = fmaxf(acc[j4 * 4 + 2], 0.0f);
        v.w = fmaxf(acc[j4 * 4 + 3], 0.0f);
        o4[j4] = v;
    }
}

// ---------------- layer-2 projection: P = h@W0 - h@W2 + b2, Q = h@W1, R = h@W2 ----------------

__global__ void gemm_proj_kernel(const float* __restrict__ h, const float* __restrict__ W,
                                 const float* __restrict__ bias,
                                 float* __restrict__ P, float* __restrict__ Q,
                                 float* __restrict__ R) {
    // Ws layout: [64][48]; j<16: W0-W2, 16..31: W1, 32..47: W2
    __shared__ float Ws[64 * 48];
    for (int i = threadIdx.x; i < 64 * 48; i += blockDim.x) {
        int k = i / 48, j = i % 48;
        float v;
        if (j < 16) v = W[k * 16 + j] - W[2 * 1024 + k * 16 + j];
        else if (j < 32) v = W[1024 + k * 16 + (j - 16)];
        else v = W[2 * 1024 + k * 16 + (j - 32)];
        Ws[i] = v;
    }
    __syncthreads();

    int n = blockIdx.x * blockDim.x + threadIdx.x;
    if (n >= N_NODES) return;

    float acc[48];
#pragma unroll
    for (int j = 0; j < 48; j++) acc[j] = 0.0f;

    const float4* h4 = (const float4*)(h + (size_t)n * 64);
#pragma unroll 4
    for (int k4 = 0; k4 < 16; k4++) {
        float4 a = h4[k4];
        float tv[4] = {a.x, a.y, a.z, a.w};
#pragma unroll
        for (int kk = 0; kk < 4; kk++) {
            float t = tv[kk];
            const float* wr = &Ws[(k4 * 4 + kk) * 48];
#pragma unroll
            for (int j = 0; j < 48; j++) acc[j] += t * wr[j];
        }
    }

    float4* P4 = (float4*)(P + (size_t)n * 16);
    float4* Q4 = (float4*)(Q + (size_t)n * 16);
    float4* R4 = (float4*)(R + (size_t)n * 16);
#pragma unroll
    for (int j4 = 0; j4 < 4; j4++) {
        float4 vp, vq, vr;
        vp.x = acc[j4 * 4 + 0] + bias[j4 * 4 + 0];
        vp.y = acc[j4 * 4 + 1] + bias[j4 * 4 + 1];
        vp.z = acc[j4 * 4 + 2] + bias[j4 * 4 + 2];
        vp.w = acc[j4 * 4 + 3] + bias[j4 * 4 + 3];
        vq.x = acc[16 + j4 * 4 + 0];
        vq.y = acc[16 + j4 * 4 + 1];
        vq.z = acc[16 + j4 * 4 + 2];
        vq.w = acc[16 + j4 * 4 + 3];
        vr.x = acc[32 + j4 * 4 + 0];
        vr.y = acc[32 + j4 * 4 + 1];
        vr.z = acc[32 + j4 * 4 + 2];
        vr.w = acc[32 + j4 * 4 + 3];
        P4[j4] = vp;
        Q4[j4] = vq;
        R4[j4] = vr;
    }
}

// ---------------- launch ----------------

extern "C" void kernel_launch(void* const* d_in, const int* in_sizes, int n_in,
                              void* d_out, int out_size, void* d_ws, size_t ws_size,
                              hipStream_t stream) {
    const float* x  = (const float*)d_in[0];
    const int* edge = (const int*)d_in[1];
    const float* W1 = (const float*)d_in[2];
    const float* b1 = (const float*)d_in[3];
    const float* W2 = (const float*)d_in[4];
    const float* b2 = (const float*)d_in[5];
    float* out = (float*)d_out;

    const int* row = edge;            // edge_index[0]
    const int* col = edge + E_EDGES;  // edge_index[1]

    // workspace layout
    char* ws = (char*)d_ws;
    size_t off = 0;
    auto alloc = [&](size_t bytes) {
        void* p = ws + off;
        off = (off + bytes + 255) & ~(size_t)255;
        return p;
    };
    unsigned int* deg    = (unsigned int*)alloc(N_NODES * 4);
    float*        dis    = (float*)alloc(N_NODES * 4);
    unsigned int* rowptr = (unsigned int*)alloc(N_NODES * 4);
    unsigned int* cursor = (unsigned int*)alloc(N_NODES * 4);
    unsigned int* bsum   = (unsigned int*)alloc(512 * 4);
    int*          ccol   = (int*)alloc((size_t)CSR_CAP * 4);
    float*        cw     = (float*)alloc((size_t)CSR_CAP * 4);
    float*        A      = (float*)alloc((size_t)N_NODES * 64 * 4);
    float*        B      = (float*)alloc((size_t)N_NODES * 64 * 4);
    float*        C      = (float*)alloc((size_t)N_NODES * 64 * 4);
    float*        P      = (float*)alloc((size_t)N_NODES * 16 * 4);
    float*        Q      = (float*)alloc((size_t)N_NODES * 16 * 4);
    float*        R      = (float*)alloc((size_t)N_NODES * 16 * 4);
    float*        S      = (float*)alloc((size_t)N_NODES * 16 * 4);

    const int nodeBlocks   = (N_NODES + 255) / 256;  // 391
    const int edgeBlocks   = (E_EDGES + 255) / 256;  // 6250
    const int spmm64Blocks = (N_NODES + 3) / 4;      // 1 wave/row
    const int spmm16Blocks = (N_NODES + 15) / 16;    // 16 lanes/row

    // ---- build norm + padded CSR ----
    hipMemsetAsync(deg, 0, N_NODES * 4, stream);
    hipMemsetAsync(ccol, 0, (size_t)CSR_CAP * 4, stream);
    hipMemsetAsync(cw, 0, (size_t)CSR_CAP * 4, stream);
    deg_kernel<<<edgeBlocks, 256, 0, stream>>>(row, col, deg);
    dis_kernel<<<nodeBlocks, 256, 0, stream>>>(deg, dis);
    scan1_kernel<<<nodeBlocks, 256, 0, stream>>>(deg, rowptr, bsum);
    scan2_kernel<<<1, 512, 0, stream>>>(bsum, nodeBlocks);
    scan3_kernel<<<nodeBlocks, 256, 0, stream>>>(rowptr, bsum, cursor);
    fill_kernel<<<edgeBlocks, 256, 0, stream>>>(row, col, dis, cursor, ccol, cw);

    // ---- layer 1: A = Lx; B = LA; C = relu(x@W1_0 + A@W1_1 + (2B-x)@W1_2 + b1) ----
    spmm64_kernel<<<spmm64Blocks, 256, 0, stream>>>(rowptr, deg, ccol, cw, x, A);
    spmm64_kernel<<<spmm64Blocks, 256, 0, stream>>>(rowptr, deg, ccol, cw, A, B);
    gemm3_64_kernel<<<nodeBlocks, 256, 0, stream>>>(x, A, B, W1, b1, C);

    // ---- layer 2 (projection-first): P,Q,R = proj(C); S = Q + 2*L(R); out = P + L(S) ----
    gemm_proj_kernel<<<nodeBlocks, 256, 0, stream>>>(C, W2, b2, P, Q, R);
    spmm16_kernel<0><<<spmm16Blocks, 256, 0, stream>>>(rowptr, deg, ccol, cw, R, Q, S);
    spmm16_kernel<1><<<spmm16Blocks, 256, 0, stream>>>(rowptr, deg, ccol, cw, S, P, out);
}